// Round 6
// baseline (307.928 us; speedup 1.0000x reference)
//
#include <hip/hip_runtime.h>

// ---------------- problem constants ----------------
#define G_DIM 3072
#define P_DIM 1024
#define ALPHA 0.1f

typedef __attribute__((ext_vector_type(8))) __bf16 bf16x8;
typedef __attribute__((ext_vector_type(4))) float  f32x4;

// workspace layout (bytes), peak 69.2 MB
#define GG2      ((size_t)G_DIM * G_DIM * 2)          // bf16 G×G = 18,874,368 B
#define S_OFF    ((size_t)0)
#define ST_OFF   (GG2)
#define X_OFF    ((size_t)0)
#define XBYTES   ((size_t)8192 * G_DIM * 2)           // 50,331,648 B
#define W_OFF    (XBYTES)

// ---------------- softmax: S = alpha * softmax(scores, -inf diag) ----------------
__global__ __launch_bounds__(256) void row_softmax_k(const float* __restrict__ gg,
                                                     __bf16* __restrict__ S) {
  const int i = blockIdx.x;
  const float* row = gg + (size_t)i * G_DIM * 2;  // [G][2], channel 1
  const int tid = threadIdx.x;
  const int lane = tid & 63, wave = tid >> 6;

  float v[12];
  float m = -INFINITY;
#pragma unroll
  for (int t = 0; t < 12; ++t) {
    int j = tid + t * 256;
    float x = row[2 * j + 1];
    if (j == i) x = -INFINITY;
    v[t] = x;
    m = fmaxf(m, x);
  }
#pragma unroll
  for (int o = 32; o; o >>= 1) m = fmaxf(m, __shfl_xor(m, o));
  __shared__ float red[4];
  if (lane == 0) red[wave] = m;
  __syncthreads();
  m = fmaxf(fmaxf(red[0], red[1]), fmaxf(red[2], red[3]));

  float s = 0.f;
#pragma unroll
  for (int t = 0; t < 12; ++t) {
    v[t] = __expf(v[t] - m);
    s += v[t];
  }
#pragma unroll
  for (int o = 32; o; o >>= 1) s += __shfl_xor(s, o);
  __syncthreads();
  if (lane == 0) red[wave] = s;
  __syncthreads();
  s = red[0] + red[1] + red[2] + red[3];

  const float scale = ALPHA / s;
  __bf16* out = S + (size_t)i * G_DIM;
#pragma unroll
  for (int t = 0; t < 12; ++t) {
    int j = tid + t * 256;
    out[j] = (__bf16)(v[t] * scale);
  }
}

// ---------------- bf16 transpose ----------------
__global__ void transpose_k(const __bf16* __restrict__ in, __bf16* __restrict__ out) {
  __shared__ __bf16 t[32][33];
  const int bx = blockIdx.x * 32, by = blockIdx.y * 32;
  const int tx = threadIdx.x, ty = threadIdx.y;
#pragma unroll
  for (int k = 0; k < 32; k += 8)
    t[ty + k][tx] = in[(size_t)(by + ty + k) * G_DIM + bx + tx];
  __syncthreads();
#pragma unroll
  for (int k = 0; k < 32; k += 8)
    out[(size_t)(bx + ty + k) * G_DIM + by + tx] = t[tx][ty + k];
}

// ---------------- deinterleave channels into X [8192][G] bf16, row = rr*2 + c ------
__global__ __launch_bounds__(384) void deinterleave_k(const float* __restrict__ pg,
                                                      const float* __restrict__ gg,
                                                      __bf16* __restrict__ X) {
  const int rr = blockIdx.x;  // 0..4095
  const float* src = (rr < P_DIM) ? (pg + (size_t)rr * G_DIM * 2)
                                  : (gg + (size_t)(rr - P_DIM) * G_DIM * 2);
  const int t = threadIdx.x;
  const float4* s4 = (const float4*)(src + (size_t)t * 16);
  float4 a = s4[0], b = s4[1], c = s4[2], d = s4[3];
  bf16x8 v0, v1;
  v0[0] = (__bf16)a.x; v1[0] = (__bf16)a.y;
  v0[1] = (__bf16)a.z; v1[1] = (__bf16)a.w;
  v0[2] = (__bf16)b.x; v1[2] = (__bf16)b.y;
  v0[3] = (__bf16)b.z; v1[3] = (__bf16)b.w;
  v0[4] = (__bf16)c.x; v1[4] = (__bf16)c.y;
  v0[5] = (__bf16)c.z; v1[5] = (__bf16)c.w;
  v0[6] = (__bf16)d.x; v1[6] = (__bf16)d.y;
  v0[7] = (__bf16)d.z; v1[7] = (__bf16)d.w;
  *(bf16x8*)(X + (size_t)(rr * 2) * G_DIM + t * 8)     = v0;
  *(bf16x8*)(X + (size_t)(rr * 2 + 1) * G_DIM + t * 8) = v1;
}

// ------- one staged global->LDS chunk (1 KiB), pre-swizzled source (rule #21) -------
// chunk covers rows [chunk*8, chunk*8+8) of a [128][64] bf16 half-tile (128 B rows),
// linear LDS dest; reader applies slot ^= (row&7)
__device__ __forceinline__ void stage1(const __bf16* __restrict__ src, size_t row0,
                                       int K, int k0, char* ldsbase, int chunk, int lane) {
  int Lb = chunk << 10;                   // wave-uniform LDS byte base
  int L  = Lb + lane * 16;                // this lane's dest byte
  int r  = L >> 7;                        // half-tile row
  int slot = ((L >> 4) & 7) ^ (r & 7);    // inverse swizzle on SOURCE
  const __bf16* g = src + (row0 + (size_t)r) * (size_t)K + (size_t)(k0 + slot * 8);
  __builtin_amdgcn_global_load_lds((const __attribute__((address_space(1))) void*)g,
                                   (__attribute__((address_space(3))) void*)(ldsbase + Lb),
                                   16, 0, 0);
}

#define MFMA16(a, b, c) __builtin_amdgcn_mfma_f32_16x16x32_bf16((a), (b), (c), 0, 0, 0)
#define LDS_RD(base, row, xx) (*(const bf16x8*)((base) + (size_t)(row) * 128 + (xx)))
#define LGKM0()  asm volatile("s_waitcnt lgkmcnt(0)" ::: "memory")
#define VM4()    asm volatile("s_waitcnt vmcnt(4)" ::: "memory")
#define BAR()    __builtin_amdgcn_s_barrier()
#define PRIO(x)  __builtin_amdgcn_s_setprio(x)

// ---------------- 8-phase NT GEMM (m201-class): C[i,j] = sum_k A[i,k]*B[j,k] --------
// BM=BN=256, BK=64, 8 waves (2M x 4N), wave tile 128x64, acc[8][4].
// LDS: 2 bufs x [A0|A1|B0|B1] 16KB halves = 128 KB. 2 K-tiles/iter, 8 phases.
// Per phase: reads -> stage 1 half -> barrier -> lgkmcnt(0) -> 16 MFMA -> barrier.
// vmcnt(4) gates at phases 4 and 8 only (2 halves in flight).
// Stage ledger (iter i; c=2i+2, d=2i+3, dp=2i+1):
//   ph1,2: dp.A0,A1->buf1 | ph3,4: c.B0,B1->buf0 | ph5,6: c.A0,A1->buf0 | ph7,8: d.B0,B1->buf1
// Drains: buf0.B end-ph2, buf0.A end-ph3, buf1.B end-ph6, buf1.A end-ph7 (all stages later).
// MODE 1: C bf16 = 0.9*(acc + e0[i,j])          (W = 0.9*(S^2 + S))
// MODE 2: d_out f32 paired = acc + 0.9*orig f32 (propagate, X row = rr*2+c)
template <int MODE>
__global__ __launch_bounds__(512, 2) void gemm8(const __bf16* __restrict__ A,
                                                const __bf16* __restrict__ B,
                                                void* __restrict__ C,
                                                const __bf16* __restrict__ e0,
                                                const float* __restrict__ pgin,
                                                const float* __restrict__ ggin,
                                                int M, int N, int K) {
  __shared__ char lds[131072];
  char* b0 = lds;
  char* b1 = lds + 65536;

  const int tid = threadIdx.x;
  const int wave = tid >> 6, lane = tid & 63;
  const int wm = wave >> 2, wn = wave & 3;   // 2M x 4N
  const int lr = lane & 15, g4 = lane >> 4;

  const size_t arow0 = (size_t)blockIdx.y * 256;
  const size_t brow0 = (size_t)blockIdx.x * 256;

  f32x4 acc[8][4] = {};
  const int NKT = K / 64;      // 48
  const int NI  = NKT / 2;     // 24

  // per-wave read bases
  char* Ah0 = b0 + wm * 16384;                    // own A half in buf0
  char* Bh0 = b0 + 32768 + (wn >> 1) * 16384;     // own B half in buf0
  char* Ah1 = b1 + wm * 16384;
  char* Bh1 = b1 + 32768 + (wn >> 1) * 16384;
  const int bcol = (wn & 1) * 64;                  // col base within B half
  const int x0 = ((g4) ^ (lr & 7)) * 16;           // ks0 swizzled slot
  const int x1 = ((4 + g4) ^ (lr & 7)) * 16;       // ks1

  const int c0c = wave * 2, c1c = wave * 2 + 1;    // this wave's 2 chunks per half

  // ---- prologue: t0 {A0,A1,B0,B1} -> buf0 ; t1 {B0,B1} -> buf1 (t1.A comes ph1,2)
  stage1(A, arow0,       K, 0,  b0,         c0c, lane);
  stage1(A, arow0,       K, 0,  b0,         c1c, lane);
  stage1(A, arow0 + 128, K, 0,  b0 + 16384, c0c, lane);
  stage1(A, arow0 + 128, K, 0,  b0 + 16384, c1c, lane);
  stage1(B, brow0,       K, 0,  b0 + 32768, c0c, lane);
  stage1(B, brow0,       K, 0,  b0 + 32768, c1c, lane);
  stage1(B, brow0 + 128, K, 0,  b0 + 49152, c0c, lane);
  stage1(B, brow0 + 128, K, 0,  b0 + 49152, c1c, lane);
  stage1(B, brow0,       K, 64, b1 + 32768, c0c, lane);
  stage1(B, brow0,       K, 64, b1 + 32768, c1c, lane);
  stage1(B, brow0 + 128, K, 64, b1 + 49152, c0c, lane);
  stage1(B, brow0 + 128, K, 64, b1 + 49152, c1c, lane);
  VM4();   // t0 fully landed (t1.B stays in flight)
  BAR();

  bf16x8 alo[4][2], ahi[4][2], blo[2][2], bhi[2][2];

  for (int i = 0; i < NI; ++i) {
    const int kdp = (2 * i + 1) * 64;
    const int kc  = (2 * i + 2) * 64;
    const int kd  = (2 * i + 3) * 64;
    const bool pc = (2 * i + 2) < NKT;
    const bool pd = (2 * i + 3) < NKT;

    // ======== K-tile 2i (buf0) ========
    // -- ph1: reads alo(8)+blo(4); stage dp.A0 -> buf1
    stage1(A, arow0,       K, kdp, b1,         c0c, lane);
    stage1(A, arow0,       K, kdp, b1,         c1c, lane);
#pragma unroll
    for (int mf = 0; mf < 4; ++mf) {
      alo[mf][0] = LDS_RD(Ah0, mf * 16 + lr, x0);
      alo[mf][1] = LDS_RD(Ah0, mf * 16 + lr, x1);
    }
#pragma unroll
    for (int nf = 0; nf < 2; ++nf) {
      blo[nf][0] = LDS_RD(Bh0, bcol + nf * 16 + lr, x0);
      blo[nf][1] = LDS_RD(Bh0, bcol + nf * 16 + lr, x1);
    }
    BAR(); LGKM0(); PRIO(1);
#pragma unroll
    for (int mf = 0; mf < 4; ++mf)
#pragma unroll
      for (int nf = 0; nf < 2; ++nf)
#pragma unroll
        for (int ks = 0; ks < 2; ++ks)
          acc[mf][nf] = MFMA16(alo[mf][ks], blo[nf][ks], acc[mf][nf]);
    PRIO(0); BAR();

    // -- ph2: reads bhi(4); stage dp.A1 -> buf1
    stage1(A, arow0 + 128, K, kdp, b1 + 16384, c0c, lane);
    stage1(A, arow0 + 128, K, kdp, b1 + 16384, c1c, lane);
#pragma unroll
    for (int nf = 0; nf < 2; ++nf) {
      bhi[nf][0] = LDS_RD(Bh0, bcol + 32 + nf * 16 + lr, x0);
      bhi[nf][1] = LDS_RD(Bh0, bcol + 32 + nf * 16 + lr, x1);
    }
    BAR(); LGKM0(); PRIO(1);
#pragma unroll
    for (int mf = 0; mf < 4; ++mf)
#pragma unroll
      for (int nf = 0; nf < 2; ++nf)
#pragma unroll
        for (int ks = 0; ks < 2; ++ks)
          acc[mf][2 + nf] = MFMA16(alo[mf][ks], bhi[nf][ks], acc[mf][2 + nf]);
    PRIO(0); BAR();

    // -- ph3: reads ahi(8); stage c.B0 -> buf0
    if (pc) {
      stage1(B, brow0,     K, kc, b0 + 32768, c0c, lane);
      stage1(B, brow0,     K, kc, b0 + 32768, c1c, lane);
    }
#pragma unroll
    for (int mf = 0; mf < 4; ++mf) {
      ahi[mf][0] = LDS_RD(Ah0, 64 + mf * 16 + lr, x0);
      ahi[mf][1] = LDS_RD(Ah0, 64 + mf * 16 + lr, x1);
    }
    BAR(); LGKM0(); PRIO(1);
#pragma unroll
    for (int mf = 0; mf < 4; ++mf)
#pragma unroll
      for (int nf = 0; nf < 2; ++nf)
#pragma unroll
        for (int ks = 0; ks < 2; ++ks)
          acc[4 + mf][2 + nf] = MFMA16(ahi[mf][ks], bhi[nf][ks], acc[4 + mf][2 + nf]);
    PRIO(0); BAR();

    // -- ph4: no reads; stage c.B1 -> buf0; GATE vmcnt(4)
    if (pc) {
      stage1(B, brow0 + 128, K, kc, b0 + 49152, c0c, lane);
      stage1(B, brow0 + 128, K, kc, b0 + 49152, c1c, lane);
    }
    VM4();
    BAR(); PRIO(1);
#pragma unroll
    for (int mf = 0; mf < 4; ++mf)
#pragma unroll
      for (int nf = 0; nf < 2; ++nf)
#pragma unroll
        for (int ks = 0; ks < 2; ++ks)
          acc[4 + mf][nf] = MFMA16(ahi[mf][ks], blo[nf][ks], acc[4 + mf][nf]);
    PRIO(0); BAR();

    // ======== K-tile 2i+1 (buf1) ========
    // -- ph5: reads alo(8)+blo(4); stage c.A0 -> buf0
    if (pc) {
      stage1(A, arow0,     K, kc, b0,         c0c, lane);
      stage1(A, arow0,     K, kc, b0,         c1c, lane);
    }
#pragma unroll
    for (int mf = 0; mf < 4; ++mf) {
      alo[mf][0] = LDS_RD(Ah1, mf * 16 + lr, x0);
      alo[mf][1] = LDS_RD(Ah1, mf * 16 + lr, x1);
    }
#pragma unroll
    for (int nf = 0; nf < 2; ++nf) {
      blo[nf][0] = LDS_RD(Bh1, bcol + nf * 16 + lr, x0);
      blo[nf][1] = LDS_RD(Bh1, bcol + nf * 16 + lr, x1);
    }
    BAR(); LGKM0(); PRIO(1);
#pragma unroll
    for (int mf = 0; mf < 4; ++mf)
#pragma unroll
      for (int nf = 0; nf < 2; ++nf)
#pragma unroll
        for (int ks = 0; ks < 2; ++ks)
          acc[mf][nf] = MFMA16(alo[mf][ks], blo[nf][ks], acc[mf][nf]);
    PRIO(0); BAR();

    // -- ph6: reads bhi(4); stage c.A1 -> buf0
    if (pc) {
      stage1(A, arow0 + 128, K, kc, b0 + 16384, c0c, lane);
      stage1(A, arow0 + 128, K, kc, b0 + 16384, c1c, lane);
    }
#pragma unroll
    for (int nf = 0; nf < 2; ++nf) {
      bhi[nf][0] = LDS_RD(Bh1, bcol + 32 + nf * 16 + lr, x0);
      bhi[nf][1] = LDS_RD(Bh1, bcol + 32 + nf * 16 + lr, x1);
    }
    BAR(); LGKM0(); PRIO(1);
#pragma unroll
    for (int mf = 0; mf < 4; ++mf)
#pragma unroll
      for (int nf = 0; nf < 2; ++nf)
#pragma unroll
        for (int ks = 0; ks < 2; ++ks)
          acc[mf][2 + nf] = MFMA16(alo[mf][ks], bhi[nf][ks], acc[mf][2 + nf]);
    PRIO(0); BAR();

    // -- ph7: reads ahi(8); stage d.B0 -> buf1
    if (pd) {
      stage1(B, brow0,     K, kd, b1 + 32768, c0c, lane);
      stage1(B, brow0,     K, kd, b1 + 32768, c1c, lane);
    }
#pragma unroll
    for (int mf = 0; mf < 4; ++mf) {
      ahi[mf][0] = LDS_RD(Ah1, 64 + mf * 16 + lr, x0);
      ahi[mf][1] = LDS_RD(Ah1, 64 + mf * 16 + lr, x1);
    }
    BAR(); LGKM0(); PRIO(1);
#pragma unroll
    for (int mf = 0; mf < 4; ++mf)
#pragma unroll
      for (int nf = 0; nf < 2; ++nf)
#pragma unroll
        for (int ks = 0; ks < 2; ++ks)
          acc[4 + mf][2 + nf] = MFMA16(ahi[mf][ks], bhi[nf][ks], acc[4 + mf][2 + nf]);
    PRIO(0); BAR();

    // -- ph8: no reads; stage d.B1 -> buf1; GATE vmcnt(4)
    if (pd) {
      stage1(B, brow0 + 128, K, kd, b1 + 49152, c0c, lane);
      stage1(B, brow0 + 128, K, kd, b1 + 49152, c1c, lane);
    }
    VM4();
    BAR(); PRIO(1);
#pragma unroll
    for (int mf = 0; mf < 4; ++mf)
#pragma unroll
      for (int nf = 0; nf < 2; ++nf)
#pragma unroll
        for (int ks = 0; ks < 2; ++ks)
          acc[4 + mf][nf] = MFMA16(ahi[mf][ks], blo[nf][ks], acc[4 + mf][nf]);
    PRIO(0); BAR();
  }

  // epilogue — C/D layout: col = lane&15, row = (lane>>4)*4 + reg  [measured m89/m91]
  const int r0 = (int)arow0 + wm * 128;
  const int c0 = (int)brow0 + wn * 64;
#pragma unroll
  for (int mf = 0; mf < 8; ++mf) {
#pragma unroll
    for (int nf = 0; nf < 4; ++nf) {
      const int col = c0 + nf * 16 + lr;
      if constexpr (MODE == 1) {
#pragma unroll
        for (int jj = 0; jj < 4; ++jj) {
          const int row = r0 + mf * 16 + g4 * 4 + jj;
          float w = 0.9f * (acc[mf][nf][jj] + (float)e0[(size_t)row * N + col]);
          ((__bf16*)C)[(size_t)row * N + col] = (__bf16)w;
        }
      } else {
        // rows come in (even,odd) pairs = (c=0, c=1) of original row rr
#pragma unroll
        for (int jp = 0; jp < 2; ++jp) {
          const int row = r0 + mf * 16 + g4 * 4 + jp * 2;  // even
          const int rr = row >> 1;
          const size_t base = (size_t)rr * G_DIM * 2 + (size_t)col * 2;
          const float* src = (rr < P_DIM) ? (pgin + base)
                                          : (ggin + base - (size_t)P_DIM * G_DIM * 2);
          float2 sv = *(const float2*)src;
          float2 ov;
          ov.x = acc[mf][nf][jp * 2]     + 0.9f * sv.x;
          ov.y = acc[mf][nf][jp * 2 + 1] + 0.9f * sv.y;
          *(float2*)((float*)C + base) = ov;
        }
      }
    }
  }
}

// ---------------- launch ----------------
extern "C" void kernel_launch(void* const* d_in, const int* in_sizes, int n_in,
                              void* d_out, int out_size, void* d_ws, size_t ws_size,
                              hipStream_t stream) {
  const float* pg = (const float*)d_in[0];  // [P,G,2] f32
  const float* gg = (const float*)d_in[1];  // [G,G,2] f32
  float* out = (float*)d_out;

  char* ws = (char*)d_ws;
  __bf16* S  = (__bf16*)(ws + S_OFF);
  __bf16* St = (__bf16*)(ws + ST_OFF);
  __bf16* W  = (__bf16*)(ws + W_OFF);
  __bf16* X  = (__bf16*)(ws + X_OFF);    // overlays S/St (dead by then)

  // 1. S = alpha * softmax(gg[:,:,1], -inf diag)      [G,G] bf16
  row_softmax_k<<<G_DIM, 256, 0, stream>>>(gg, S);
  // 2. St = S^T
  transpose_k<<<dim3(96, 96), dim3(32, 8), 0, stream>>>(S, St);
  // 3. W = 0.9*(S*S + S)   (NT: A=S, B=St; epilogue adds S, scales)
  gemm8<1><<<dim3(12, 12), 512, 0, stream>>>(S, St, W, S,
                                             nullptr, nullptr, G_DIM, G_DIM, G_DIM);
  // 4. X[rr*2+c][g] = bf16(src[rr][g][c])
  deinterleave_k<<<4096, 384, 0, stream>>>(pg, gg, X);
  // 5. out = X * W^T + 0.9 * X_f32, paired channels into d_out
  gemm8<2><<<dim3(12, 32), 512, 0, stream>>>(X, W, out, nullptr,
                                             pg, gg, 8192, G_DIM, G_DIM);
  (void)in_sizes; (void)n_in; (void)out_size; (void)ws_size;
}

// Round 7
// 253.005 us; speedup vs baseline: 1.2171x; 1.2171x over previous
//
#include <hip/hip_runtime.h>

// ---------------- problem constants ----------------
#define G_DIM 3072
#define P_DIM 1024
#define ALPHA 0.1f

typedef __attribute__((ext_vector_type(8))) __bf16 bf16x8;
typedef __attribute__((ext_vector_type(4))) float  f32x4;

// workspace layout (bytes), peak 69.2 MB
#define GG2      ((size_t)G_DIM * G_DIM * 2)          // bf16 G×G = 18,874,368 B
#define S_OFF    ((size_t)0)
#define ST_OFF   (GG2)
#define X_OFF    ((size_t)0)
#define XBYTES   ((size_t)8192 * G_DIM * 2)           // 50,331,648 B
#define W_OFF    (XBYTES)

// ---------------- softmax: S = alpha * softmax(scores, -inf diag) ----------------
__global__ __launch_bounds__(256) void row_softmax_k(const float* __restrict__ gg,
                                                     __bf16* __restrict__ S) {
  const int i = blockIdx.x;
  const float* row = gg + (size_t)i * G_DIM * 2;  // [G][2], channel 1
  const int tid = threadIdx.x;
  const int lane = tid & 63, wave = tid >> 6;

  float v[12];
  float m = -INFINITY;
#pragma unroll
  for (int t = 0; t < 12; ++t) {
    int j = tid + t * 256;
    float x = row[2 * j + 1];
    if (j == i) x = -INFINITY;
    v[t] = x;
    m = fmaxf(m, x);
  }
#pragma unroll
  for (int o = 32; o; o >>= 1) m = fmaxf(m, __shfl_xor(m, o));
  __shared__ float red[4];
  if (lane == 0) red[wave] = m;
  __syncthreads();
  m = fmaxf(fmaxf(red[0], red[1]), fmaxf(red[2], red[3]));

  float s = 0.f;
#pragma unroll
  for (int t = 0; t < 12; ++t) {
    v[t] = __expf(v[t] - m);
    s += v[t];
  }
#pragma unroll
  for (int o = 32; o; o >>= 1) s += __shfl_xor(s, o);
  __syncthreads();
  if (lane == 0) red[wave] = s;
  __syncthreads();
  s = red[0] + red[1] + red[2] + red[3];

  const float scale = ALPHA / s;
  __bf16* out = S + (size_t)i * G_DIM;
#pragma unroll
  for (int t = 0; t < 12; ++t) {
    int j = tid + t * 256;
    out[j] = (__bf16)(v[t] * scale);
  }
}

// ---------------- bf16 transpose ----------------
__global__ void transpose_k(const __bf16* __restrict__ in, __bf16* __restrict__ out) {
  __shared__ __bf16 t[32][33];
  const int bx = blockIdx.x * 32, by = blockIdx.y * 32;
  const int tx = threadIdx.x, ty = threadIdx.y;
#pragma unroll
  for (int k = 0; k < 32; k += 8)
    t[ty + k][tx] = in[(size_t)(by + ty + k) * G_DIM + bx + tx];
  __syncthreads();
#pragma unroll
  for (int k = 0; k < 32; k += 8)
    out[(size_t)(bx + ty + k) * G_DIM + by + tx] = t[tx][ty + k];
}

// ---------------- deinterleave channels into X [8192][G] bf16, row = rr*2 + c ------
__global__ __launch_bounds__(384) void deinterleave_k(const float* __restrict__ pg,
                                                      const float* __restrict__ gg,
                                                      __bf16* __restrict__ X) {
  const int rr = blockIdx.x;  // 0..4095
  const float* src = (rr < P_DIM) ? (pg + (size_t)rr * G_DIM * 2)
                                  : (gg + (size_t)(rr - P_DIM) * G_DIM * 2);
  const int t = threadIdx.x;
  const float4* s4 = (const float4*)(src + (size_t)t * 16);
  float4 a = s4[0], b = s4[1], c = s4[2], d = s4[3];
  bf16x8 v0, v1;
  v0[0] = (__bf16)a.x; v1[0] = (__bf16)a.y;
  v0[1] = (__bf16)a.z; v1[1] = (__bf16)a.w;
  v0[2] = (__bf16)b.x; v1[2] = (__bf16)b.y;
  v0[3] = (__bf16)b.z; v1[3] = (__bf16)b.w;
  v0[4] = (__bf16)c.x; v1[4] = (__bf16)c.y;
  v0[5] = (__bf16)c.z; v1[5] = (__bf16)c.w;
  v0[6] = (__bf16)d.x; v1[6] = (__bf16)d.y;
  v0[7] = (__bf16)d.z; v1[7] = (__bf16)d.w;
  *(bf16x8*)(X + (size_t)(rr * 2) * G_DIM + t * 8)     = v0;
  *(bf16x8*)(X + (size_t)(rr * 2 + 1) * G_DIM + t * 8) = v1;
}

// ------- one staged global->LDS chunk (1 KiB), pre-swizzled source (rule #21) -------
// chunk covers rows [chunk*8, chunk*8+8) of a [rows][64] bf16 region (128 B rows),
// linear LDS dest; reader applies slot ^= (row&7)
__device__ __forceinline__ void stage1(const __bf16* __restrict__ src, size_t row0,
                                       int K, int k0, char* ldsbase, int chunk, int lane) {
  int Lb = chunk << 10;                   // wave-uniform LDS byte base
  int L  = Lb + lane * 16;                // this lane's dest byte
  int r  = L >> 7;                        // region row
  int slot = ((L >> 4) & 7) ^ (r & 7);    // inverse swizzle on SOURCE
  const __bf16* g = src + (row0 + (size_t)r) * (size_t)K + (size_t)(k0 + slot * 8);
  __builtin_amdgcn_global_load_lds((const __attribute__((address_space(1))) void*)g,
                                   (__attribute__((address_space(3))) void*)(ldsbase + Lb),
                                   16, 0, 0);
}

#define MFMA16(a, b, c) __builtin_amdgcn_mfma_f32_16x16x32_bf16((a), (b), (c), 0, 0, 0)
#define LDS_RD(base, row, xx) (*(const bf16x8*)((base) + (size_t)(row) * 128 + (xx)))
#define LGKM0()  asm volatile("s_waitcnt lgkmcnt(0)" ::: "memory")
#define VM3()    asm volatile("s_waitcnt vmcnt(3)" ::: "memory")
#define VM0()    asm volatile("s_waitcnt vmcnt(0)" ::: "memory")
#define BAR()    __builtin_amdgcn_s_barrier()
#define PRIO(x)  __builtin_amdgcn_s_setprio(x)

// -------- 256x192 double-buffered NT GEMM, 3 phases / K-tile, 2 barriers / K-tile ----
// 8 waves (2M x 4N), wave tile 128x48, acc[8][3]. LDS: 2 bufs x (A 32K | B 24K) = 112KB.
// Per-wave loads/K-tile = 7 (A0:2 ph1, A1:2 ph2 -> next buf; B:3 ph3 -> tile t+2, cur buf).
// Gate: vmcnt(3) before BAR#2 proves tile t+1 (B:3 + A:4) landed, B_{t+2}:3 in flight.
// Every barrier is preceded by an asm-"memory" fence (no load hoists across).
// MODE 1: C bf16 = 0.9*(acc + e0[i,j])          (W = 0.9*(S^2 + S))
// MODE 2: d_out f32 paired = acc + 0.9*orig f32 (propagate, X row = rr*2+c)
template <int MODE>
__global__ __launch_bounds__(512, 2) void gemm3p(const __bf16* __restrict__ A,
                                                 const __bf16* __restrict__ B,
                                                 void* __restrict__ C,
                                                 const __bf16* __restrict__ e0,
                                                 const float* __restrict__ pgin,
                                                 const float* __restrict__ ggin,
                                                 int M, int N, int K) {
  __shared__ char lds[114688];   // 2 x (32 KiB A + 24 KiB B)

  const int tid = threadIdx.x;
  const int wave = tid >> 6, lane = tid & 63;
  const int wm = wave >> 2, wn = wave & 3;   // 2M x 4N
  const int lr = lane & 15, g4 = lane >> 4;

  const size_t arow0 = (size_t)blockIdx.x * 256;   // bx = M-tile (L2: consecutive bids share B-panel)
  const size_t brow0 = (size_t)blockIdx.y * 192;

  f32x4 acc[8][3] = {};
  const int NT = K / 64;

  const int a2w = wave * 2;      // A chunk base (2 chunks/wave per 128-row half)
  const int b3w = wave * 3;      // B chunk base (3 chunks/wave per 192-row tile)
  const int x0 = ((g4) ^ (lr & 7)) * 16;        // ks0 swizzled slot byte
  const int x1 = ((4 + g4) ^ (lr & 7)) * 16;    // ks1

  // prologue: tile0 {A0,A1,B} + tile1 {B}; gate tile0 (oldest 7 of 10)
  {
    char* b0 = lds;
    char* b1 = lds + 57344;
    stage1(A, arow0,       K, 0,  b0,         a2w, lane);
    stage1(A, arow0,       K, 0,  b0,         a2w + 1, lane);
    stage1(A, arow0 + 128, K, 0,  b0 + 16384, a2w, lane);
    stage1(A, arow0 + 128, K, 0,  b0 + 16384, a2w + 1, lane);
    stage1(B, brow0,       K, 0,  b0 + 32768, b3w, lane);
    stage1(B, brow0,       K, 0,  b0 + 32768, b3w + 1, lane);
    stage1(B, brow0,       K, 0,  b0 + 32768, b3w + 2, lane);
    stage1(B, brow0,       K, 64, b1 + 32768, b3w, lane);
    stage1(B, brow0,       K, 64, b1 + 32768, b3w + 1, lane);
    stage1(B, brow0,       K, 64, b1 + 32768, b3w + 2, lane);
  }
  VM3();
  BAR();

  for (int t = 0; t < NT; ++t) {
    char* buf = lds + (t & 1) * 57344;
    char* nxt = lds + ((t + 1) & 1) * 57344;
    char* Ab = buf + wm * 16384;     // this wave's 128-row A half
    char* Bb = buf + 32768;
    const int kn = (t + 1) * 64;
    const int k2 = (t + 2) * 64;
    const bool pa = (t + 1) < NT;
    const bool pb = (t + 2) < NT;

    bf16x8 alo[4][2], ahi[4][2], b01[2][2], b2[2];

    // ---- ph1: stage A0_{t+1} -> nxt; read alo + b01; MFMA alo x b01 (16) ----
    if (pa) {
      stage1(A, arow0, K, kn, nxt, a2w, lane);
      stage1(A, arow0, K, kn, nxt, a2w + 1, lane);
    }
#pragma unroll
    for (int mf = 0; mf < 4; ++mf) {
      alo[mf][0] = LDS_RD(Ab, mf * 16 + lr, x0);
      alo[mf][1] = LDS_RD(Ab, mf * 16 + lr, x1);
    }
#pragma unroll
    for (int nf = 0; nf < 2; ++nf) {
      b01[nf][0] = LDS_RD(Bb, wn * 48 + nf * 16 + lr, x0);
      b01[nf][1] = LDS_RD(Bb, wn * 48 + nf * 16 + lr, x1);
    }
    PRIO(1);
#pragma unroll
    for (int mf = 0; mf < 4; ++mf)
#pragma unroll
      for (int nf = 0; nf < 2; ++nf)
#pragma unroll
        for (int ks = 0; ks < 2; ++ks)
          acc[mf][nf] = MFMA16(alo[mf][ks], b01[nf][ks], acc[mf][nf]);
    PRIO(0);

    // ---- ph2: stage A1_{t+1} -> nxt; read ahi + b2; MFMA (alo,ahi) x b2 (16) ----
    if (pa) {
      stage1(A, arow0 + 128, K, kn, nxt + 16384, a2w, lane);
      stage1(A, arow0 + 128, K, kn, nxt + 16384, a2w + 1, lane);
    }
#pragma unroll
    for (int mf = 0; mf < 4; ++mf) {
      ahi[mf][0] = LDS_RD(Ab, 64 + mf * 16 + lr, x0);
      ahi[mf][1] = LDS_RD(Ab, 64 + mf * 16 + lr, x1);
    }
    b2[0] = LDS_RD(Bb, wn * 48 + 32 + lr, x0);
    b2[1] = LDS_RD(Bb, wn * 48 + 32 + lr, x1);
    PRIO(1);
#pragma unroll
    for (int mf = 0; mf < 4; ++mf)
#pragma unroll
      for (int ks = 0; ks < 2; ++ks) {
        acc[mf][2]     = MFMA16(alo[mf][ks], b2[ks], acc[mf][2]);
        acc[4 + mf][2] = MFMA16(ahi[mf][ks], b2[ks], acc[4 + mf][2]);
      }
    PRIO(0);
    LGKM0();   // all this tile's LDS reads complete (cross-wave, via BAR below)
    BAR();     // BAR#1: safe to overwrite buf.B

    // ---- ph3: stage B_{t+2} -> buf; MFMA ahi x b01 (16); gate; BAR#2 ----
    if (pb) {
      stage1(B, brow0, K, k2, Bb, b3w, lane);
      stage1(B, brow0, K, k2, Bb, b3w + 1, lane);
      stage1(B, brow0, K, k2, Bb, b3w + 2, lane);
    }
    PRIO(1);
#pragma unroll
    for (int mf = 0; mf < 4; ++mf)
#pragma unroll
      for (int nf = 0; nf < 2; ++nf)
#pragma unroll
        for (int ks = 0; ks < 2; ++ks)
          acc[4 + mf][nf] = MFMA16(ahi[mf][ks], b01[nf][ks], acc[4 + mf][nf]);
    PRIO(0);
    if (t >= NT - 2) VM0(); else VM3();   // tile t+1 fully landed for all waves
    BAR();     // BAR#2
  }

  // epilogue — C/D layout: col = lane&15, row = (lane>>4)*4 + reg  [measured m89/m91]
  const int r0 = (int)arow0 + wm * 128;
  const int c0 = (int)brow0 + wn * 48;
#pragma unroll
  for (int mf = 0; mf < 8; ++mf) {
#pragma unroll
    for (int nf = 0; nf < 3; ++nf) {
      const int col = c0 + nf * 16 + lr;
      if constexpr (MODE == 1) {
#pragma unroll
        for (int jj = 0; jj < 4; ++jj) {
          const int row = r0 + mf * 16 + g4 * 4 + jj;
          float w = 0.9f * (acc[mf][nf][jj] + (float)e0[(size_t)row * N + col]);
          ((__bf16*)C)[(size_t)row * N + col] = (__bf16)w;
        }
      } else {
        // rows come in (even,odd) pairs = (c=0, c=1) of original row rr
#pragma unroll
        for (int jp = 0; jp < 2; ++jp) {
          const int row = r0 + mf * 16 + g4 * 4 + jp * 2;  // even
          const int rr = row >> 1;
          const size_t base = (size_t)rr * G_DIM * 2 + (size_t)col * 2;
          const float* src = (rr < P_DIM) ? (pgin + base)
                                          : (ggin + base - (size_t)P_DIM * G_DIM * 2);
          float2 sv = *(const float2*)src;
          float2 ov;
          ov.x = acc[mf][nf][jp * 2]     + 0.9f * sv.x;
          ov.y = acc[mf][nf][jp * 2 + 1] + 0.9f * sv.y;
          *(float2*)((float*)C + base) = ov;
        }
      }
    }
  }
}

// ---------------- launch ----------------
extern "C" void kernel_launch(void* const* d_in, const int* in_sizes, int n_in,
                              void* d_out, int out_size, void* d_ws, size_t ws_size,
                              hipStream_t stream) {
  const float* pg = (const float*)d_in[0];  // [P,G,2] f32
  const float* gg = (const float*)d_in[1];  // [G,G,2] f32
  float* out = (float*)d_out;

  char* ws = (char*)d_ws;
  __bf16* S  = (__bf16*)(ws + S_OFF);
  __bf16* St = (__bf16*)(ws + ST_OFF);
  __bf16* W  = (__bf16*)(ws + W_OFF);
  __bf16* X  = (__bf16*)(ws + X_OFF);    // overlays S/St (dead by then)

  // 1. S = alpha * softmax(gg[:,:,1], -inf diag)      [G,G] bf16
  row_softmax_k<<<G_DIM, 256, 0, stream>>>(gg, S);
  // 2. St = S^T
  transpose_k<<<dim3(96, 96), dim3(32, 8), 0, stream>>>(S, St);
  // 3. W = 0.9*(S*S + S)   (NT: A=S, B=St; epilogue adds S, scales)
  gemm3p<1><<<dim3(12, 16), 512, 0, stream>>>(S, St, W, S,
                                              nullptr, nullptr, G_DIM, G_DIM, G_DIM);
  // 4. X[rr*2+c][g] = bf16(src[rr][g][c])
  deinterleave_k<<<4096, 384, 0, stream>>>(pg, gg, X);
  // 5. out = X * W^T + 0.9 * X_f32, paired channels into d_out
  gemm3p<2><<<dim3(32, 16), 512, 0, stream>>>(X, W, out, nullptr,
                                              pg, gg, 8192, G_DIM, G_DIM);
  (void)in_sizes; (void)n_in; (void)out_size; (void)ws_size;
}